// Round 12
// baseline (314.185 us; speedup 1.0000x reference)
//
#include <hip/hip_runtime.h>
#include <hip/hip_fp16.h>

#define N_NODES 10000
#define N_EDGES 30000
#define NODE_DIM 75
#define BOND_DIM 16
#define IN_DIM 64
#define INTERNAL 128
#define FP_DIM 4096
#define N_GRAPHS 16
#define DEPTH 3

typedef _Float16 half8v __attribute__((ext_vector_type(8)));
typedef float float4v __attribute__((ext_vector_type(4)));

// msg0 = relu(x @ W_ae + b_ae); writes fp32 + fp16; 4 nodes/block
__global__ void k_atom_expand(const float* __restrict__ x, const float* __restrict__ W,
                              const float* __restrict__ b, float* __restrict__ msg,
                              __half* __restrict__ msg16) {
    int tid = threadIdx.x;
    int q = tid >> 6;                     // 0..3
    int o = tid & 63;
    int n = blockIdx.x * 4 + q;
    __shared__ float xr[4][NODE_DIM];
    if (o < NODE_DIM) xr[q][o] = x[(size_t)n * NODE_DIM + o];
    if (o + 64 < NODE_DIM) xr[q][o + 64] = x[(size_t)n * NODE_DIM + o + 64];
    __syncthreads();
    float acc = b[o];
    #pragma unroll
    for (int k = 0; k < NODE_DIM; ++k) acc = fmaf(xr[q][k], W[k * IN_DIM + o], acc);
    float v = fmaxf(acc, 0.f);
    msg[(size_t)n * IN_DIM + o] = v;
    msg16[(size_t)n * IN_DIM + o] = __float2half(v);
}

// h = relu(edge_attr @ W_e1 + b_e1) -> fp16 (2 edges/block), PLUS (fused):
//  - per-dst mask counts; graph bounds search; zeroing of agg
__global__ void k_edge_h16(const float* __restrict__ ea, const float* __restrict__ W1,
                           const float* __restrict__ b1, __half* __restrict__ h,
                           const int* __restrict__ dst,
                           float* __restrict__ cntC, float* __restrict__ cntS,
                           const int* __restrict__ batch, int* __restrict__ gstart,
                           float* __restrict__ agg0) {
    const int tid = threadIdx.x;
    const int q = tid >> 7;                       // 0/1
    const int j = tid & 127;
    const int e = blockIdx.x * 2 + q;
    __shared__ float r[2][BOND_DIM];
    if (j < BOND_DIM) r[q][j] = ea[(size_t)e * BOND_DIM + j];

    if (blockIdx.x < 1250)
        ((float2*)agg0)[(size_t)blockIdx.x * 256 + tid] = (float2){0.f, 0.f};
    if (blockIdx.x == 0 && tid <= N_GRAPHS) {
        int g = tid, lo = 0, hi = N_NODES;
        while (lo < hi) { int mid = (lo + hi) >> 1; if (batch[mid] < g) lo = mid + 1; else hi = mid; }
        gstart[g] = lo;
    }
    __syncthreads();
    if (j == 0) {
        if (r[q][BOND_DIM - 1] == 0.f) atomicAdd(&cntC[dst[e]], 1.f);
        else                           atomicAdd(&cntS[dst[e]], 1.f);
    }
    float acc = b1[j];
    #pragma unroll
    for (int k = 0; k < BOND_DIM; ++k) acc = fmaf(r[q][k], W1[k * INTERNAL + j], acc);
    h[(size_t)e * INTERNAL + j] = __float2half(fmaxf(acc, 0.f));
}

// Fused LDS-tiled transposes: blocks 0..63 -> W2T, blocks 64..127 -> WfpT
__global__ void k_wt(const float* __restrict__ W2, const float* __restrict__ Wfp,
                     __half* __restrict__ W2T, __half* __restrict__ WfpT) {
    __shared__ _Float16 t[64][136];
    const int tid = threadIdx.x;                   // 256
    if (blockIdx.x < 64) {
        const int n0 = blockIdx.x * 64;
        #pragma unroll
        for (int i = 0; i < 32; ++i) {
            int k = (tid >> 6) + 4 * i;            // 0..127
            int n = tid & 63;
            t[n][k] = (_Float16)W2[(size_t)k * 4096 + n0 + n];
        }
        __syncthreads();
        const int nr = tid >> 2;
        const int kc = (tid & 3) * 32;
        _Float16* dstp = (_Float16*)W2T + (size_t)(n0 + nr) * INTERNAL + kc;
        const _Float16* srcp = &t[nr][kc];
        #pragma unroll
        for (int j = 0; j < 4; ++j)
            *(half8v*)(dstp + 8 * j) = *(const half8v*)(srcp + 8 * j);
    } else {
        const int n0 = (blockIdx.x - 64) * 64;
        #pragma unroll
        for (int i = 0; i < 16; ++i) {
            int k = (tid >> 6) + 4 * i;            // 0..63
            int n = tid & 63;
            t[n][k] = (_Float16)Wfp[(size_t)k * 4096 + n0 + n];
        }
        __syncthreads();
        const int nr = tid >> 2;
        const int kc = (tid & 3) * 16;
        _Float16* dstp = (_Float16*)WfpT + (size_t)(n0 + nr) * IN_DIM + kc;
        const _Float16* srcp = &t[nr][kc];
        *(half8v*)(dstp)     = *(const half8v*)(srcp);
        *(half8v*)(dstp + 8) = *(const half8v*)(srcp + 8);
    }
}

// One-time MFMA GEMM: w[E,4096] = h16[E,128] @ W2 + b2, fp16 row-major.
// Block = 8 waves x 32 edges, n-block 128; B panel in LDS. Epilogue: FOUR
// passes of 8 edges (st[8][8][136]) -> LDS 52.2 KB -> 3 blocks/CU.
__global__ __launch_bounds__(512) void k_wgemm(
    const __half* __restrict__ h16, const __half* __restrict__ W2T,
    const float* __restrict__ b2, __half* __restrict__ w)
{
    __shared__ _Float16 B[128][136];
    __shared__ _Float16 st[8][8][136];
    const int tid  = threadIdx.x;
    const int lane = tid & 63;
    const int wv   = tid >> 6;
    const int nbase = blockIdx.x * 128;
    const int ebase = blockIdx.y * 256 + wv * 32;
    const int l15 = lane & 15;
    const int kq  = (lane >> 4) * 8;
    const int g   = lane >> 4;            // 0..3

    const _Float16* hp = (const _Float16*)h16;
    const _Float16* wp = (const _Float16*)W2T;

    half8v a[2][4];
    #pragma unroll
    for (int mi = 0; mi < 2; ++mi) {
        int e = ebase + mi * 16 + l15;
        if (e >= N_EDGES) e = N_EDGES - 1;
        const _Float16* arow = hp + (size_t)e * INTERNAL;
        #pragma unroll
        for (int kk = 0; kk < 4; ++kk)
            a[mi][kk] = *(const half8v*)(arow + kk * 32 + kq);
    }
    float bias[8];
    #pragma unroll
    for (int ni = 0; ni < 8; ++ni) bias[ni] = b2[nbase + ni * 16 + l15];

    {
        int r  = tid >> 2;
        int c0 = (tid & 3) * 32;
        const _Float16* srcp = wp + (size_t)(nbase + r) * INTERNAL + c0;
        *(half8v*)&B[r][c0]      = *(const half8v*)(srcp);
        *(half8v*)&B[r][c0 + 8]  = *(const half8v*)(srcp + 8);
        *(half8v*)&B[r][c0 + 16] = *(const half8v*)(srcp + 16);
        *(half8v*)&B[r][c0 + 24] = *(const half8v*)(srcp + 24);
    }
    __syncthreads();

    float4v acc[2][8];
    #pragma unroll
    for (int mi = 0; mi < 2; ++mi)
        #pragma unroll
        for (int ni = 0; ni < 8; ++ni)
            acc[mi][ni] = (float4v){0.f, 0.f, 0.f, 0.f};

    #pragma unroll
    for (int kk = 0; kk < 4; ++kk) {
        half8v bw[8];
        #pragma unroll
        for (int ni = 0; ni < 8; ++ni)
            bw[ni] = *(const half8v*)&B[ni * 16 + l15][kk * 32 + kq];
        #pragma unroll
        for (int ni = 0; ni < 8; ++ni) {
            acc[0][ni] = __builtin_amdgcn_mfma_f32_16x16x32_f16(a[0][kk], bw[ni], acc[0][ni], 0, 0, 0);
            acc[1][ni] = __builtin_amdgcn_mfma_f32_16x16x32_f16(a[1][kk], bw[ni], acc[1][ni], 0, 0, 0);
        }
    }

    // four-pass epilogue: pass covers 8 edge rows (mi = pass>>1, half = (pass&1)*8).
    // Lane-group g holds rows g*4..g*4+3 of an mi-block; groups with
    // (g>>1)==(pass&1) stage this pass. Wave-private LDS: in-order, no barrier.
    #pragma unroll
    for (int pass = 0; pass < 4; ++pass) {
        const int mi = pass >> 1;
        const int half = (pass & 1) * 8;
        if ((g >> 1) == (pass & 1)) {
            int rowInPass = g * 4 - half;          // 0 or 4
            #pragma unroll
            for (int ni = 0; ni < 8; ++ni)
                #pragma unroll
                for (int r = 0; r < 4; ++r)
                    st[wv][rowInPass + r][ni * 16 + l15] = (_Float16)(acc[mi][ni][r] + bias[ni]);
        }
        #pragma unroll
        for (int it = 0; it < 2; ++it) {
            int erow = it * 4 + g;                 // 0..7
            half8v v = *(const half8v*)&st[wv][erow][l15 * 8];
            int e = ebase + mi * 16 + half + erow;
            if (e < N_EDGES)
                *(half8v*)((_Float16*)w + (size_t)e * FP_DIM + nbase + l15 * 8) = v;
        }
    }
}

// Per depth: per_edge[e] = m[src[e]] @ w[e], pre-scaled by 1/cnt{mask}[dst],
// single-agg scatter. Persistent waves, TWO-deep software pipeline.
__global__ __launch_bounds__(256) void k_edge_apply(
    const float* __restrict__ msg, const __half* __restrict__ w,
    const int* __restrict__ src, const int* __restrict__ dst,
    const float* __restrict__ ea,
    const float* __restrict__ cntC, const float* __restrict__ cntS,
    float* __restrict__ agg)
{
    const int lane = threadIdx.x & 63;
    const int ig = lane >> 3;
    const int oc = lane & 7;
    const int nw = (int)gridDim.x * 4;
    int e = (int)blockIdx.x * 4 + ((int)threadIdx.x >> 6);
    if (e >= N_EDGES) return;

    auto LOAD = [&](int ee, float& mv, half8v* w8, int& dv, float& sc) {
        mv = msg[(size_t)src[ee] * IN_DIM + lane];
        const half8v* wr = (const half8v*)((const _Float16*)w + (size_t)ee * FP_DIM);
        #pragma unroll
        for (int t = 0; t < 8; ++t) w8[t] = wr[(ig + 8 * t) * 8 + oc];
        dv = dst[ee];
        sc = 1.0f / ((ea[(size_t)ee * BOND_DIM + (BOND_DIM - 1)] == 0.f)
                     ? cntC[dv] : cntS[dv]);
    };
    auto PROC = [&](float mv, const half8v* w8, int dv, float sc) {
        float acc[8] = {0.f, 0.f, 0.f, 0.f, 0.f, 0.f, 0.f, 0.f};
        #pragma unroll
        for (int t = 0; t < 8; ++t) {
            float mi = __shfl(mv, ig + 8 * t);
            #pragma unroll
            for (int j = 0; j < 8; ++j) acc[j] = fmaf(mi, (float)w8[t][j], acc[j]);
        }
        #pragma unroll
        for (int d = 8; d < 64; d <<= 1)
            #pragma unroll
            for (int j = 0; j < 8; ++j) acc[j] += __shfl_xor(acc[j], d);
        float v = (ig == 0) ? acc[0] : (ig == 1) ? acc[1] : (ig == 2) ? acc[2] :
                  (ig == 3) ? acc[3] : (ig == 4) ? acc[4] : (ig == 5) ? acc[5] :
                  (ig == 6) ? acc[6] : acc[7];
        atomicAdd(&agg[(size_t)dv * IN_DIM + oc * 8 + ig], v * sc);
    };

    float mvA, scA; int dvA; half8v wA[8];
    float mvB, scB; int dvB; half8v wB[8];
    LOAD(e, mvA, wA, dvA, scA);
    bool hasB = (e + nw < N_EDGES);
    if (hasB) LOAD(e + nw, mvB, wB, dvB, scB);

    while (true) {
        bool hasC = (e + 2 * nw < N_EDGES);
        PROC(mvA, wA, dvA, scA);
        if (hasC) LOAD(e + 2 * nw, mvA, wA, dvA, scA);
        if (!hasB) break;
        bool hasD = (e + 3 * nw < N_EDGES);
        PROC(mvB, wB, dvB, scB);
        if (hasD) LOAD(e + 3 * nw, mvB, wB, dvB, scB);
        if (!hasC) break;
        e += 2 * nw;
        hasB = hasD;
    }
}

// msg_new = relu(agg + 2*(msg_old @ W_root + b_conv)); fp32 + fp16.
// 4 nodes/block; zeroes agg in-place for the next depth.
__global__ void k_combine(const float* __restrict__ msg_old, const float* __restrict__ Wr,
                          const float* __restrict__ bc,
                          float* __restrict__ agg,
                          float* __restrict__ msg_new, __half* __restrict__ msg16) {
    int tid = threadIdx.x;
    int n = blockIdx.x * 4 + (tid >> 6);
    int o = tid & 63;
    int q = tid >> 6;
    __shared__ float r[4][IN_DIM];
    r[q][o] = msg_old[(size_t)n * IN_DIM + o];
    __syncthreads();
    float root = bc[o];
    #pragma unroll
    for (int k = 0; k < IN_DIM; ++k) root = fmaf(r[q][k], Wr[k * IN_DIM + o], root);
    size_t idx = (size_t)n * IN_DIM + o;
    float a = agg[idx];
    agg[idx] = 0.f;
    float v = fmaxf(a + 2.f * root, 0.f);
    msg_new[idx] = v;
    msg16[idx] = __float2half(v);
}

// MFMA fused GEMM + relu + add-pool: out[g,:] += sum_n relu(msg16[n] @ WfpT^T + b_fp)
__global__ __launch_bounds__(256) void k_fp_pool_mfma(
    const __half* __restrict__ msg16, const __half* __restrict__ WfpT,
    const float* __restrict__ bfp, const int* __restrict__ gstart,
    float* __restrict__ out)
{
    const int tid = threadIdx.x, lane = tid & 63, wid = tid >> 6;
    const int g = blockIdx.y;
    const int cbase = blockIdx.x * 256 + wid * 64;
    const int l15 = lane & 15;
    const int kq = (lane >> 4) * 8;
    const int rq = (lane >> 4) * 4;

    const _Float16* wt = (const _Float16*)WfpT;
    const _Float16* mp = (const _Float16*)msg16;

    half8v bf[4][2];
    float bias[4];
    #pragma unroll
    for (int nf = 0; nf < 4; ++nf) {
        int n = cbase + nf * 16 + l15;
        #pragma unroll
        for (int kk = 0; kk < 2; ++kk)
            bf[nf][kk] = *(const half8v*)(wt + (size_t)n * IN_DIM + kk * 32 + kq);
        bias[nf] = bfp[n];
    }

    int n0g = gstart[g], n1g = gstart[g + 1];
    int len = n1g - n0g;
    int chunk = (len + (int)gridDim.z - 1) / (int)gridDim.z;
    int rs = n0g + (int)blockIdx.z * chunk;
    int re = min(rs + chunk, n1g);
    if (rs >= re) return;

    float pool[4] = {0.f, 0.f, 0.f, 0.f};
    int node0 = rs + l15; if (node0 >= n1g) node0 = n1g - 1;
    half8v af0 = *(const half8v*)(mp + (size_t)node0 * IN_DIM + kq);
    half8v af1 = *(const half8v*)(mp + (size_t)node0 * IN_DIM + 32 + kq);
    for (int r = rs; r < re; r += 16) {
        half8v nf0 = af0, nf1 = af1;
        if (r + 16 < re) {
            int node = r + 16 + l15; if (node >= n1g) node = n1g - 1;
            nf0 = *(const half8v*)(mp + (size_t)node * IN_DIM + kq);
            nf1 = *(const half8v*)(mp + (size_t)node * IN_DIM + 32 + kq);
        }
        #pragma unroll
        for (int nf = 0; nf < 4; ++nf) {
            float4v d = (float4v){0.f, 0.f, 0.f, 0.f};
            d = __builtin_amdgcn_mfma_f32_16x16x32_f16(af0, bf[nf][0], d, 0, 0, 0);
            d = __builtin_amdgcn_mfma_f32_16x16x32_f16(af1, bf[nf][1], d, 0, 0, 0);
            #pragma unroll
            for (int reg = 0; reg < 4; ++reg) {
                int rr = r + rq + reg;
                if (rr < re) pool[nf] += fmaxf(d[reg] + bias[nf], 0.f);
            }
        }
        af0 = nf0; af1 = nf1;
    }
    #pragma unroll
    for (int nf = 0; nf < 4; ++nf) {
        pool[nf] += __shfl_xor(pool[nf], 16);
        pool[nf] += __shfl_xor(pool[nf], 32);
    }
    if (lane < 16) {
        #pragma unroll
        for (int nf = 0; nf < 4; ++nf)
            atomicAdd(&out[(size_t)g * FP_DIM + cbase + nf * 16 + lane], pool[nf]);
    }
}

extern "C" void kernel_launch(void* const* d_in, const int* in_sizes, int n_in,
                              void* d_out, int out_size, void* d_ws, size_t ws_size,
                              hipStream_t stream) {
    const float* x        = (const float*)d_in[0];
    const int*   eidx     = (const int*)d_in[1];
    const float* ea       = (const float*)d_in[2];
    const int*   batch    = (const int*)d_in[3];
    const float* W_ae     = (const float*)d_in[4];
    const float* b_ae     = (const float*)d_in[5];
    const float* W_e1     = (const float*)d_in[6];
    const float* b_e1     = (const float*)d_in[7];
    const float* W_e2     = (const float*)d_in[8];
    const float* b_e2     = (const float*)d_in[9];
    const float* W_root   = (const float*)d_in[10];
    const float* b_conv   = (const float*)d_in[11];
    const float* W_fp     = (const float*)d_in[12];
    const float* b_fp     = (const float*)d_in[13];
    const int* src = eidx;
    const int* dst = eidx + N_EDGES;
    float* out = (float*)d_out;

    hipMemsetAsync(out, 0, (size_t)out_size * sizeof(float), stream);

    float* ws   = (float*)d_ws;
    float* msgA = ws;
    float* msgB = msgA + 640000;
    float* aggC = msgB + 640000;
    float* aggS = aggC + 640000;                        // unused (layout keep)
    float* cntC = aggS + 640000;
    float* cntS = cntC + 10000;
    int*   gst  = (int*)(cntS + 10000);                 // 32 ints

    __half* h16   = (__half*)(gst + 32);
    __half* W2T   = h16 + (size_t)N_EDGES * INTERNAL;
    __half* wbig  = W2T + (size_t)FP_DIM * INTERNAL;
    __half* msg16 = wbig + (size_t)N_EDGES * FP_DIM;
    __half* WfpT  = msg16 + (size_t)N_NODES * IN_DIM;

    size_t need = (4ull * 640000 + 2 * 10000 + 32) * 4
                + ((size_t)N_EDGES * INTERNAL + (size_t)FP_DIM * INTERNAL
                   + (size_t)N_EDGES * FP_DIM + (size_t)N_NODES * IN_DIM
                   + (size_t)FP_DIM * IN_DIM) * 2;
    if (ws_size < need) return;   // fail loudly (out stays 0)

    hipMemsetAsync(cntC, 0, 2 * (size_t)N_NODES * sizeof(float), stream);
    k_atom_expand<<<N_NODES / 4, 256, 0, stream>>>(x, W_ae, b_ae, msgA, msg16);
    k_edge_h16<<<N_EDGES / 2, 256, 0, stream>>>(ea, W_e1, b_e1, h16,
                                                dst, cntC, cntS, batch, gst, aggC);
    k_wt<<<128, 256, 0, stream>>>(W_e2, W_fp, W2T, WfpT);
    k_wgemm<<<dim3(FP_DIM / 128, (N_EDGES + 255) / 256), 512, 0, stream>>>(
        h16, W2T, b_e2, wbig);

    float* cur = msgA;
    float* nxt = msgB;
    for (int d = 0; d < DEPTH; ++d) {
        k_edge_apply<<<1024, 256, 0, stream>>>(
            cur, wbig, src, dst, ea, cntC, cntS, aggC);
        k_combine<<<N_NODES / 4, 256, 0, stream>>>(cur, W_root, b_conv, aggC,
                                                   nxt, msg16);
        k_fp_pool_mfma<<<dim3(FP_DIM / 256, N_GRAPHS, 4), 256, 0, stream>>>(
            msg16, WfpT, b_fp, gst, out);
        float* t = cur; cur = nxt; nxt = t;
    }
}

// Round 13
// 288.223 us; speedup vs baseline: 1.0901x; 1.0901x over previous
//
#include <hip/hip_runtime.h>
#include <hip/hip_fp16.h>

#define N_NODES 10000
#define N_EDGES 30000
#define NODE_DIM 75
#define BOND_DIM 16
#define IN_DIM 64
#define INTERNAL 128
#define FP_DIM 4096
#define N_GRAPHS 16
#define DEPTH 3

typedef _Float16 half8v __attribute__((ext_vector_type(8)));
typedef float float4v __attribute__((ext_vector_type(4)));

// msg0 = relu(x @ W_ae + b_ae); writes fp32 + fp16; 4 nodes/block
__global__ void k_atom_expand(const float* __restrict__ x, const float* __restrict__ W,
                              const float* __restrict__ b, float* __restrict__ msg,
                              __half* __restrict__ msg16) {
    int tid = threadIdx.x;
    int q = tid >> 6;                     // 0..3
    int o = tid & 63;
    int n = blockIdx.x * 4 + q;
    __shared__ float xr[4][NODE_DIM];
    if (o < NODE_DIM) xr[q][o] = x[(size_t)n * NODE_DIM + o];
    if (o + 64 < NODE_DIM) xr[q][o + 64] = x[(size_t)n * NODE_DIM + o + 64];
    __syncthreads();
    float acc = b[o];
    #pragma unroll
    for (int k = 0; k < NODE_DIM; ++k) acc = fmaf(xr[q][k], W[k * IN_DIM + o], acc);
    float v = fmaxf(acc, 0.f);
    msg[(size_t)n * IN_DIM + o] = v;
    msg16[(size_t)n * IN_DIM + o] = __float2half(v);
}

// h = relu(edge_attr @ W_e1 + b_e1) -> fp16 (2 edges/block), PLUS (fused):
//  - per-dst mask counts; graph bounds search; zeroing of agg
__global__ void k_edge_h16(const float* __restrict__ ea, const float* __restrict__ W1,
                           const float* __restrict__ b1, __half* __restrict__ h,
                           const int* __restrict__ dst,
                           float* __restrict__ cntC, float* __restrict__ cntS,
                           const int* __restrict__ batch, int* __restrict__ gstart,
                           float* __restrict__ agg0) {
    const int tid = threadIdx.x;
    const int q = tid >> 7;                       // 0/1
    const int j = tid & 127;
    const int e = blockIdx.x * 2 + q;
    __shared__ float r[2][BOND_DIM];
    if (j < BOND_DIM) r[q][j] = ea[(size_t)e * BOND_DIM + j];

    if (blockIdx.x < 1250)
        ((float2*)agg0)[(size_t)blockIdx.x * 256 + tid] = (float2){0.f, 0.f};
    if (blockIdx.x == 0 && tid <= N_GRAPHS) {
        int g = tid, lo = 0, hi = N_NODES;
        while (lo < hi) { int mid = (lo + hi) >> 1; if (batch[mid] < g) lo = mid + 1; else hi = mid; }
        gstart[g] = lo;
    }
    __syncthreads();
    if (j == 0) {
        if (r[q][BOND_DIM - 1] == 0.f) atomicAdd(&cntC[dst[e]], 1.f);
        else                           atomicAdd(&cntS[dst[e]], 1.f);
    }
    float acc = b1[j];
    #pragma unroll
    for (int k = 0; k < BOND_DIM; ++k) acc = fmaf(r[q][k], W1[k * INTERNAL + j], acc);
    h[(size_t)e * INTERNAL + j] = __float2half(fmaxf(acc, 0.f));
}

// Fused LDS-tiled transposes: blocks 0..63 -> W2T, blocks 64..127 -> WfpT
__global__ void k_wt(const float* __restrict__ W2, const float* __restrict__ Wfp,
                     __half* __restrict__ W2T, __half* __restrict__ WfpT) {
    __shared__ _Float16 t[64][136];
    const int tid = threadIdx.x;                   // 256
    if (blockIdx.x < 64) {
        const int n0 = blockIdx.x * 64;
        #pragma unroll
        for (int i = 0; i < 32; ++i) {
            int k = (tid >> 6) + 4 * i;            // 0..127
            int n = tid & 63;
            t[n][k] = (_Float16)W2[(size_t)k * 4096 + n0 + n];
        }
        __syncthreads();
        const int nr = tid >> 2;
        const int kc = (tid & 3) * 32;
        _Float16* dstp = (_Float16*)W2T + (size_t)(n0 + nr) * INTERNAL + kc;
        const _Float16* srcp = &t[nr][kc];
        #pragma unroll
        for (int j = 0; j < 4; ++j)
            *(half8v*)(dstp + 8 * j) = *(const half8v*)(srcp + 8 * j);
    } else {
        const int n0 = (blockIdx.x - 64) * 64;
        #pragma unroll
        for (int i = 0; i < 16; ++i) {
            int k = (tid >> 6) + 4 * i;            // 0..63
            int n = tid & 63;
            t[n][k] = (_Float16)Wfp[(size_t)k * 4096 + n0 + n];
        }
        __syncthreads();
        const int nr = tid >> 2;
        const int kc = (tid & 3) * 16;
        _Float16* dstp = (_Float16*)WfpT + (size_t)(n0 + nr) * IN_DIM + kc;
        const _Float16* srcp = &t[nr][kc];
        *(half8v*)(dstp)     = *(const half8v*)(srcp);
        *(half8v*)(dstp + 8) = *(const half8v*)(srcp + 8);
    }
}

// One-time MFMA GEMM: w[E,4096] = h16[E,128] @ W2 + b2, fp16 row-major.
// R11-proven structure: 8 waves x 32 edges, B panel in LDS, TWO-pass
// wave-private transpose epilogue (st[8][16][136], 69.6 KB total, 2 blocks/CU).
__global__ __launch_bounds__(512) void k_wgemm(
    const __half* __restrict__ h16, const __half* __restrict__ W2T,
    const float* __restrict__ b2, __half* __restrict__ w)
{
    __shared__ _Float16 B[128][136];
    __shared__ _Float16 st[8][16][136];
    const int tid  = threadIdx.x;
    const int lane = tid & 63;
    const int wv   = tid >> 6;
    const int nbase = blockIdx.x * 128;
    const int ebase = blockIdx.y * 256 + wv * 32;
    const int l15 = lane & 15;
    const int kq  = (lane >> 4) * 8;

    const _Float16* hp = (const _Float16*)h16;
    const _Float16* wp = (const _Float16*)W2T;

    half8v a[2][4];
    #pragma unroll
    for (int mi = 0; mi < 2; ++mi) {
        int e = ebase + mi * 16 + l15;
        if (e >= N_EDGES) e = N_EDGES - 1;
        const _Float16* arow = hp + (size_t)e * INTERNAL;
        #pragma unroll
        for (int kk = 0; kk < 4; ++kk)
            a[mi][kk] = *(const half8v*)(arow + kk * 32 + kq);
    }
    float bias[8];
    #pragma unroll
    for (int ni = 0; ni < 8; ++ni) bias[ni] = b2[nbase + ni * 16 + l15];

    {
        int r  = tid >> 2;
        int c0 = (tid & 3) * 32;
        const _Float16* srcp = wp + (size_t)(nbase + r) * INTERNAL + c0;
        *(half8v*)&B[r][c0]      = *(const half8v*)(srcp);
        *(half8v*)&B[r][c0 + 8]  = *(const half8v*)(srcp + 8);
        *(half8v*)&B[r][c0 + 16] = *(const half8v*)(srcp + 16);
        *(half8v*)&B[r][c0 + 24] = *(const half8v*)(srcp + 24);
    }
    __syncthreads();

    float4v acc[2][8];
    #pragma unroll
    for (int mi = 0; mi < 2; ++mi)
        #pragma unroll
        for (int ni = 0; ni < 8; ++ni)
            acc[mi][ni] = (float4v){0.f, 0.f, 0.f, 0.f};

    #pragma unroll
    for (int kk = 0; kk < 4; ++kk) {
        half8v bw[8];
        #pragma unroll
        for (int ni = 0; ni < 8; ++ni)
            bw[ni] = *(const half8v*)&B[ni * 16 + l15][kk * 32 + kq];
        #pragma unroll
        for (int ni = 0; ni < 8; ++ni) {
            acc[0][ni] = __builtin_amdgcn_mfma_f32_16x16x32_f16(a[0][kk], bw[ni], acc[0][ni], 0, 0, 0);
            acc[1][ni] = __builtin_amdgcn_mfma_f32_16x16x32_f16(a[1][kk], bw[ni], acc[1][ni], 0, 0, 0);
        }
    }

    const int rq = (lane >> 4) * 4;
    #pragma unroll
    for (int mi = 0; mi < 2; ++mi) {
        #pragma unroll
        for (int ni = 0; ni < 8; ++ni)
            #pragma unroll
            for (int r = 0; r < 4; ++r)
                st[wv][rq + r][ni * 16 + l15] = (_Float16)(acc[mi][ni][r] + bias[ni]);
        #pragma unroll
        for (int it = 0; it < 4; ++it) {
            int erow = it * 4 + (lane >> 4);
            half8v v = *(const half8v*)&st[wv][erow][l15 * 8];
            int e = ebase + mi * 16 + erow;
            if (e < N_EDGES)
                *(half8v*)((_Float16*)w + (size_t)e * FP_DIM + nbase + l15 * 8) = v;
        }
    }
}

// Per depth: per_edge[e] = m[src[e]] @ w[e], pre-scaled by 1/cnt{mask}[dst],
// single-agg scatter. Persistent waves, TWO-deep software pipeline.
__global__ __launch_bounds__(256) void k_edge_apply(
    const float* __restrict__ msg, const __half* __restrict__ w,
    const int* __restrict__ src, const int* __restrict__ dst,
    const float* __restrict__ ea,
    const float* __restrict__ cntC, const float* __restrict__ cntS,
    float* __restrict__ agg)
{
    const int lane = threadIdx.x & 63;
    const int ig = lane >> 3;
    const int oc = lane & 7;
    const int nw = (int)gridDim.x * 4;
    int e = (int)blockIdx.x * 4 + ((int)threadIdx.x >> 6);
    if (e >= N_EDGES) return;

    auto LOAD = [&](int ee, float& mv, half8v* w8, int& dv, float& sc) {
        mv = msg[(size_t)src[ee] * IN_DIM + lane];
        const half8v* wr = (const half8v*)((const _Float16*)w + (size_t)ee * FP_DIM);
        #pragma unroll
        for (int t = 0; t < 8; ++t) w8[t] = wr[(ig + 8 * t) * 8 + oc];
        dv = dst[ee];
        sc = 1.0f / ((ea[(size_t)ee * BOND_DIM + (BOND_DIM - 1)] == 0.f)
                     ? cntC[dv] : cntS[dv]);
    };
    auto PROC = [&](float mv, const half8v* w8, int dv, float sc) {
        float acc[8] = {0.f, 0.f, 0.f, 0.f, 0.f, 0.f, 0.f, 0.f};
        #pragma unroll
        for (int t = 0; t < 8; ++t) {
            float mi = __shfl(mv, ig + 8 * t);
            #pragma unroll
            for (int j = 0; j < 8; ++j) acc[j] = fmaf(mi, (float)w8[t][j], acc[j]);
        }
        #pragma unroll
        for (int d = 8; d < 64; d <<= 1)
            #pragma unroll
            for (int j = 0; j < 8; ++j) acc[j] += __shfl_xor(acc[j], d);
        float v = (ig == 0) ? acc[0] : (ig == 1) ? acc[1] : (ig == 2) ? acc[2] :
                  (ig == 3) ? acc[3] : (ig == 4) ? acc[4] : (ig == 5) ? acc[5] :
                  (ig == 6) ? acc[6] : acc[7];
        atomicAdd(&agg[(size_t)dv * IN_DIM + oc * 8 + ig], v * sc);
    };

    float mvA, scA; int dvA; half8v wA[8];
    float mvB, scB; int dvB; half8v wB[8];
    LOAD(e, mvA, wA, dvA, scA);
    bool hasB = (e + nw < N_EDGES);
    if (hasB) LOAD(e + nw, mvB, wB, dvB, scB);

    while (true) {
        bool hasC = (e + 2 * nw < N_EDGES);
        PROC(mvA, wA, dvA, scA);
        if (hasC) LOAD(e + 2 * nw, mvA, wA, dvA, scA);
        if (!hasB) break;
        bool hasD = (e + 3 * nw < N_EDGES);
        PROC(mvB, wB, dvB, scB);
        if (hasD) LOAD(e + 3 * nw, mvB, wB, dvB, scB);
        if (!hasC) break;
        e += 2 * nw;
        hasB = hasD;
    }
}

// msg_new = relu(agg + 2*(msg_old @ W_root + b_conv)); fp32 + fp16.
// 4 nodes/block; zeroes agg in-place for the next depth.
__global__ void k_combine(const float* __restrict__ msg_old, const float* __restrict__ Wr,
                          const float* __restrict__ bc,
                          float* __restrict__ agg,
                          float* __restrict__ msg_new, __half* __restrict__ msg16) {
    int tid = threadIdx.x;
    int n = blockIdx.x * 4 + (tid >> 6);
    int o = tid & 63;
    int q = tid >> 6;
    __shared__ float r[4][IN_DIM];
    r[q][o] = msg_old[(size_t)n * IN_DIM + o];
    __syncthreads();
    float root = bc[o];
    #pragma unroll
    for (int k = 0; k < IN_DIM; ++k) root = fmaf(r[q][k], Wr[k * IN_DIM + o], root);
    size_t idx = (size_t)n * IN_DIM + o;
    float a = agg[idx];
    agg[idx] = 0.f;
    float v = fmaxf(a + 2.f * root, 0.f);
    msg_new[idx] = v;
    msg16[idx] = __float2half(v);
}

// MFMA fused GEMM + relu + add-pool: out[g,:] += sum_n relu(msg16[n] @ WfpT^T + b_fp)
__global__ __launch_bounds__(256) void k_fp_pool_mfma(
    const __half* __restrict__ msg16, const __half* __restrict__ WfpT,
    const float* __restrict__ bfp, const int* __restrict__ gstart,
    float* __restrict__ out)
{
    const int tid = threadIdx.x, lane = tid & 63, wid = tid >> 6;
    const int g = blockIdx.y;
    const int cbase = blockIdx.x * 256 + wid * 64;
    const int l15 = lane & 15;
    const int kq = (lane >> 4) * 8;
    const int rq = (lane >> 4) * 4;

    const _Float16* wt = (const _Float16*)WfpT;
    const _Float16* mp = (const _Float16*)msg16;

    half8v bf[4][2];
    float bias[4];
    #pragma unroll
    for (int nf = 0; nf < 4; ++nf) {
        int n = cbase + nf * 16 + l15;
        #pragma unroll
        for (int kk = 0; kk < 2; ++kk)
            bf[nf][kk] = *(const half8v*)(wt + (size_t)n * IN_DIM + kk * 32 + kq);
        bias[nf] = bfp[n];
    }

    int n0g = gstart[g], n1g = gstart[g + 1];
    int len = n1g - n0g;
    int chunk = (len + (int)gridDim.z - 1) / (int)gridDim.z;
    int rs = n0g + (int)blockIdx.z * chunk;
    int re = min(rs + chunk, n1g);
    if (rs >= re) return;

    float pool[4] = {0.f, 0.f, 0.f, 0.f};
    int node0 = rs + l15; if (node0 >= n1g) node0 = n1g - 1;
    half8v af0 = *(const half8v*)(mp + (size_t)node0 * IN_DIM + kq);
    half8v af1 = *(const half8v*)(mp + (size_t)node0 * IN_DIM + 32 + kq);
    for (int r = rs; r < re; r += 16) {
        half8v nf0 = af0, nf1 = af1;
        if (r + 16 < re) {
            int node = r + 16 + l15; if (node >= n1g) node = n1g - 1;
            nf0 = *(const half8v*)(mp + (size_t)node * IN_DIM + kq);
            nf1 = *(const half8v*)(mp + (size_t)node * IN_DIM + 32 + kq);
        }
        #pragma unroll
        for (int nf = 0; nf < 4; ++nf) {
            float4v d = (float4v){0.f, 0.f, 0.f, 0.f};
            d = __builtin_amdgcn_mfma_f32_16x16x32_f16(af0, bf[nf][0], d, 0, 0, 0);
            d = __builtin_amdgcn_mfma_f32_16x16x32_f16(af1, bf[nf][1], d, 0, 0, 0);
            #pragma unroll
            for (int reg = 0; reg < 4; ++reg) {
                int rr = r + rq + reg;
                if (rr < re) pool[nf] += fmaxf(d[reg] + bias[nf], 0.f);
            }
        }
        af0 = nf0; af1 = nf1;
    }
    #pragma unroll
    for (int nf = 0; nf < 4; ++nf) {
        pool[nf] += __shfl_xor(pool[nf], 16);
        pool[nf] += __shfl_xor(pool[nf], 32);
    }
    if (lane < 16) {
        #pragma unroll
        for (int nf = 0; nf < 4; ++nf)
            atomicAdd(&out[(size_t)g * FP_DIM + cbase + nf * 16 + lane], pool[nf]);
    }
}

extern "C" void kernel_launch(void* const* d_in, const int* in_sizes, int n_in,
                              void* d_out, int out_size, void* d_ws, size_t ws_size,
                              hipStream_t stream) {
    const float* x        = (const float*)d_in[0];
    const int*   eidx     = (const int*)d_in[1];
    const float* ea       = (const float*)d_in[2];
    const int*   batch    = (const int*)d_in[3];
    const float* W_ae     = (const float*)d_in[4];
    const float* b_ae     = (const float*)d_in[5];
    const float* W_e1     = (const float*)d_in[6];
    const float* b_e1     = (const float*)d_in[7];
    const float* W_e2     = (const float*)d_in[8];
    const float* b_e2     = (const float*)d_in[9];
    const float* W_root   = (const float*)d_in[10];
    const float* b_conv   = (const float*)d_in[11];
    const float* W_fp     = (const float*)d_in[12];
    const float* b_fp     = (const float*)d_in[13];
    const int* src = eidx;
    const int* dst = eidx + N_EDGES;
    float* out = (float*)d_out;

    hipMemsetAsync(out, 0, (size_t)out_size * sizeof(float), stream);

    float* ws   = (float*)d_ws;
    float* msgA = ws;
    float* msgB = msgA + 640000;
    float* aggC = msgB + 640000;
    float* aggS = aggC + 640000;                        // unused (layout keep)
    float* cntC = aggS + 640000;
    float* cntS = cntC + 10000;
    int*   gst  = (int*)(cntS + 10000);                 // 32 ints

    __half* h16   = (__half*)(gst + 32);
    __half* W2T   = h16 + (size_t)N_EDGES * INTERNAL;
    __half* wbig  = W2T + (size_t)FP_DIM * INTERNAL;
    __half* msg16 = wbig + (size_t)N_EDGES * FP_DIM;
    __half* WfpT  = msg16 + (size_t)N_NODES * IN_DIM;

    size_t need = (4ull * 640000 + 2 * 10000 + 32) * 4
                + ((size_t)N_EDGES * INTERNAL + (size_t)FP_DIM * INTERNAL
                   + (size_t)N_EDGES * FP_DIM + (size_t)N_NODES * IN_DIM
                   + (size_t)FP_DIM * IN_DIM) * 2;
    if (ws_size < need) return;   // fail loudly (out stays 0)

    hipMemsetAsync(cntC, 0, 2 * (size_t)N_NODES * sizeof(float), stream);
    k_atom_expand<<<N_NODES / 4, 256, 0, stream>>>(x, W_ae, b_ae, msgA, msg16);
    k_edge_h16<<<N_EDGES / 2, 256, 0, stream>>>(ea, W_e1, b_e1, h16,
                                                dst, cntC, cntS, batch, gst, aggC);
    k_wt<<<128, 256, 0, stream>>>(W_e2, W_fp, W2T, WfpT);
    k_wgemm<<<dim3(FP_DIM / 128, (N_EDGES + 255) / 256), 512, 0, stream>>>(
        h16, W2T, b_e2, wbig);

    float* cur = msgA;
    float* nxt = msgB;
    for (int d = 0; d < DEPTH; ++d) {
        k_edge_apply<<<1024, 256, 0, stream>>>(
            cur, wbig, src, dst, ea, cntC, cntS, aggC);
        k_combine<<<N_NODES / 4, 256, 0, stream>>>(cur, W_root, b_conv, aggC,
                                                   nxt, msg16);
        k_fp_pool_mfma<<<dim3(FP_DIM / 256, N_GRAPHS, 4), 256, 0, stream>>>(
            msg16, WfpT, b_fp, gst, out);
        float* t = cur; cur = nxt; nxt = t;
    }
}

// Round 14
// 286.740 us; speedup vs baseline: 1.0957x; 1.0052x over previous
//
#include <hip/hip_runtime.h>
#include <hip/hip_fp16.h>

#define N_NODES 10000
#define N_EDGES 30000
#define NODE_DIM 75
#define BOND_DIM 16
#define IN_DIM 64
#define INTERNAL 128
#define FP_DIM 4096
#define N_GRAPHS 16
#define DEPTH 3

typedef _Float16 half8v __attribute__((ext_vector_type(8)));
typedef float float4v __attribute__((ext_vector_type(4)));

// msg0 = relu(x @ W_ae + b_ae); writes fp32 + fp16; 4 nodes/block
__global__ void k_atom_expand(const float* __restrict__ x, const float* __restrict__ W,
                              const float* __restrict__ b, float* __restrict__ msg,
                              __half* __restrict__ msg16) {
    int tid = threadIdx.x;
    int q = tid >> 6;                     // 0..3
    int o = tid & 63;
    int n = blockIdx.x * 4 + q;
    __shared__ float xr[4][NODE_DIM];
    if (o < NODE_DIM) xr[q][o] = x[(size_t)n * NODE_DIM + o];
    if (o + 64 < NODE_DIM) xr[q][o + 64] = x[(size_t)n * NODE_DIM + o + 64];
    __syncthreads();
    float acc = b[o];
    #pragma unroll
    for (int k = 0; k < NODE_DIM; ++k) acc = fmaf(xr[q][k], W[k * IN_DIM + o], acc);
    float v = fmaxf(acc, 0.f);
    msg[(size_t)n * IN_DIM + o] = v;
    msg16[(size_t)n * IN_DIM + o] = __float2half(v);
}

// h = relu(edge_attr @ W_e1 + b_e1) -> fp16 (2 edges/block), PLUS (fused):
//  - per-dst mask counts; graph bounds search; zeroing of agg
__global__ void k_edge_h16(const float* __restrict__ ea, const float* __restrict__ W1,
                           const float* __restrict__ b1, __half* __restrict__ h,
                           const int* __restrict__ dst,
                           float* __restrict__ cntC, float* __restrict__ cntS,
                           const int* __restrict__ batch, int* __restrict__ gstart,
                           float* __restrict__ agg0) {
    const int tid = threadIdx.x;
    const int q = tid >> 7;                       // 0/1
    const int j = tid & 127;
    const int e = blockIdx.x * 2 + q;
    __shared__ float r[2][BOND_DIM];
    if (j < BOND_DIM) r[q][j] = ea[(size_t)e * BOND_DIM + j];

    if (blockIdx.x < 1250)
        ((float2*)agg0)[(size_t)blockIdx.x * 256 + tid] = (float2){0.f, 0.f};
    if (blockIdx.x == 0 && tid <= N_GRAPHS) {
        int g = tid, lo = 0, hi = N_NODES;
        while (lo < hi) { int mid = (lo + hi) >> 1; if (batch[mid] < g) lo = mid + 1; else hi = mid; }
        gstart[g] = lo;
    }
    __syncthreads();
    if (j == 0) {
        if (r[q][BOND_DIM - 1] == 0.f) atomicAdd(&cntC[dst[e]], 1.f);
        else                           atomicAdd(&cntS[dst[e]], 1.f);
    }
    float acc = b1[j];
    #pragma unroll
    for (int k = 0; k < BOND_DIM; ++k) acc = fmaf(r[q][k], W1[k * INTERNAL + j], acc);
    h[(size_t)e * INTERNAL + j] = __float2half(fmaxf(acc, 0.f));
}

// Fused LDS-tiled transposes: blocks 0..63 -> W2T, blocks 64..127 -> WfpT
__global__ void k_wt(const float* __restrict__ W2, const float* __restrict__ Wfp,
                     __half* __restrict__ W2T, __half* __restrict__ WfpT) {
    __shared__ _Float16 t[64][136];
    const int tid = threadIdx.x;                   // 256
    if (blockIdx.x < 64) {
        const int n0 = blockIdx.x * 64;
        #pragma unroll
        for (int i = 0; i < 32; ++i) {
            int k = (tid >> 6) + 4 * i;            // 0..127
            int n = tid & 63;
            t[n][k] = (_Float16)W2[(size_t)k * 4096 + n0 + n];
        }
        __syncthreads();
        const int nr = tid >> 2;
        const int kc = (tid & 3) * 32;
        _Float16* dstp = (_Float16*)W2T + (size_t)(n0 + nr) * INTERNAL + kc;
        const _Float16* srcp = &t[nr][kc];
        #pragma unroll
        for (int j = 0; j < 4; ++j)
            *(half8v*)(dstp + 8 * j) = *(const half8v*)(srcp + 8 * j);
    } else {
        const int n0 = (blockIdx.x - 64) * 64;
        #pragma unroll
        for (int i = 0; i < 16; ++i) {
            int k = (tid >> 6) + 4 * i;            // 0..63
            int n = tid & 63;
            t[n][k] = (_Float16)Wfp[(size_t)k * 4096 + n0 + n];
        }
        __syncthreads();
        const int nr = tid >> 2;
        const int kc = (tid & 3) * 16;
        _Float16* dstp = (_Float16*)WfpT + (size_t)(n0 + nr) * IN_DIM + kc;
        const _Float16* srcp = &t[nr][kc];
        *(half8v*)(dstp)     = *(const half8v*)(srcp);
        *(half8v*)(dstp + 8) = *(const half8v*)(srcp + 8);
    }
}

// One-time MFMA GEMM: w[E,4096] = h16[E,128] @ W2 + b2, fp16 row-major.
// R11 structure + LDS ALIASING: the B panel (34.8 KB) is dead after the MFMA
// loop; the transpose stage (same 34.8 KB) is only live after it. One shared
// array + one barrier -> LDS 34.8 KB total -> 4 blocks/CU (max waves).
__global__ __launch_bounds__(512) void k_wgemm(
    const __half* __restrict__ h16, const __half* __restrict__ W2T,
    const float* __restrict__ b2, __half* __restrict__ w)
{
    __shared__ _Float16 Bst[128][136];    // B panel, then per-wave transpose stage
    const int tid  = threadIdx.x;
    const int lane = tid & 63;
    const int wv   = tid >> 6;
    const int nbase = blockIdx.x * 128;
    const int ebase = blockIdx.y * 256 + wv * 32;
    const int l15 = lane & 15;
    const int kq  = (lane >> 4) * 8;

    const _Float16* hp = (const _Float16*)h16;
    const _Float16* wp = (const _Float16*)W2T;

    half8v a[2][4];
    #pragma unroll
    for (int mi = 0; mi < 2; ++mi) {
        int e = ebase + mi * 16 + l15;
        if (e >= N_EDGES) e = N_EDGES - 1;
        const _Float16* arow = hp + (size_t)e * INTERNAL;
        #pragma unroll
        for (int kk = 0; kk < 4; ++kk)
            a[mi][kk] = *(const half8v*)(arow + kk * 32 + kq);
    }
    float bias[8];
    #pragma unroll
    for (int ni = 0; ni < 8; ++ni) bias[ni] = b2[nbase + ni * 16 + l15];

    {
        int r  = tid >> 2;
        int c0 = (tid & 3) * 32;
        const _Float16* srcp = wp + (size_t)(nbase + r) * INTERNAL + c0;
        *(half8v*)&Bst[r][c0]      = *(const half8v*)(srcp);
        *(half8v*)&Bst[r][c0 + 8]  = *(const half8v*)(srcp + 8);
        *(half8v*)&Bst[r][c0 + 16] = *(const half8v*)(srcp + 16);
        *(half8v*)&Bst[r][c0 + 24] = *(const half8v*)(srcp + 24);
    }
    __syncthreads();

    float4v acc[2][8];
    #pragma unroll
    for (int mi = 0; mi < 2; ++mi)
        #pragma unroll
        for (int ni = 0; ni < 8; ++ni)
            acc[mi][ni] = (float4v){0.f, 0.f, 0.f, 0.f};

    #pragma unroll
    for (int kk = 0; kk < 4; ++kk) {
        half8v bw[8];
        #pragma unroll
        for (int ni = 0; ni < 8; ++ni)
            bw[ni] = *(const half8v*)&Bst[ni * 16 + l15][kk * 32 + kq];
        #pragma unroll
        for (int ni = 0; ni < 8; ++ni) {
            acc[0][ni] = __builtin_amdgcn_mfma_f32_16x16x32_f16(a[0][kk], bw[ni], acc[0][ni], 0, 0, 0);
            acc[1][ni] = __builtin_amdgcn_mfma_f32_16x16x32_f16(a[1][kk], bw[ni], acc[1][ni], 0, 0, 0);
        }
    }
    __syncthreads();   // all waves done reading B before stage overwrites it

    // per-wave stage region: 16 rows x 136 halfs inside Bst
    _Float16* st = &Bst[0][0] + (size_t)wv * 16 * 136;
    const int rq = (lane >> 4) * 4;
    #pragma unroll
    for (int mi = 0; mi < 2; ++mi) {
        #pragma unroll
        for (int ni = 0; ni < 8; ++ni)
            #pragma unroll
            for (int r = 0; r < 4; ++r)
                st[(rq + r) * 136 + ni * 16 + l15] = (_Float16)(acc[mi][ni][r] + bias[ni]);
        #pragma unroll
        for (int it = 0; it < 4; ++it) {
            int erow = it * 4 + (lane >> 4);
            half8v v = *(const half8v*)&st[erow * 136 + l15 * 8];
            int e = ebase + mi * 16 + erow;
            if (e < N_EDGES)
                *(half8v*)((_Float16*)w + (size_t)e * FP_DIM + nbase + l15 * 8) = v;
        }
    }
}

// Per depth: per_edge[e] = m[src[e]] @ w[e], pre-scaled by 1/cnt{mask}[dst],
// single-agg scatter. Persistent waves, TWO-deep software pipeline.
__global__ __launch_bounds__(256) void k_edge_apply(
    const float* __restrict__ msg, const __half* __restrict__ w,
    const int* __restrict__ src, const int* __restrict__ dst,
    const float* __restrict__ ea,
    const float* __restrict__ cntC, const float* __restrict__ cntS,
    float* __restrict__ agg)
{
    const int lane = threadIdx.x & 63;
    const int ig = lane >> 3;
    const int oc = lane & 7;
    const int nw = (int)gridDim.x * 4;
    int e = (int)blockIdx.x * 4 + ((int)threadIdx.x >> 6);
    if (e >= N_EDGES) return;

    auto LOAD = [&](int ee, float& mv, half8v* w8, int& dv, float& sc) {
        mv = msg[(size_t)src[ee] * IN_DIM + lane];
        const half8v* wr = (const half8v*)((const _Float16*)w + (size_t)ee * FP_DIM);
        #pragma unroll
        for (int t = 0; t < 8; ++t) w8[t] = wr[(ig + 8 * t) * 8 + oc];
        dv = dst[ee];
        sc = 1.0f / ((ea[(size_t)ee * BOND_DIM + (BOND_DIM - 1)] == 0.f)
                     ? cntC[dv] : cntS[dv]);
    };
    auto PROC = [&](float mv, const half8v* w8, int dv, float sc) {
        float acc[8] = {0.f, 0.f, 0.f, 0.f, 0.f, 0.f, 0.f, 0.f};
        #pragma unroll
        for (int t = 0; t < 8; ++t) {
            float mi = __shfl(mv, ig + 8 * t);
            #pragma unroll
            for (int j = 0; j < 8; ++j) acc[j] = fmaf(mi, (float)w8[t][j], acc[j]);
        }
        #pragma unroll
        for (int d = 8; d < 64; d <<= 1)
            #pragma unroll
            for (int j = 0; j < 8; ++j) acc[j] += __shfl_xor(acc[j], d);
        float v = (ig == 0) ? acc[0] : (ig == 1) ? acc[1] : (ig == 2) ? acc[2] :
                  (ig == 3) ? acc[3] : (ig == 4) ? acc[4] : (ig == 5) ? acc[5] :
                  (ig == 6) ? acc[6] : acc[7];
        atomicAdd(&agg[(size_t)dv * IN_DIM + oc * 8 + ig], v * sc);
    };

    float mvA, scA; int dvA; half8v wA[8];
    float mvB, scB; int dvB; half8v wB[8];
    LOAD(e, mvA, wA, dvA, scA);
    bool hasB = (e + nw < N_EDGES);
    if (hasB) LOAD(e + nw, mvB, wB, dvB, scB);

    while (true) {
        bool hasC = (e + 2 * nw < N_EDGES);
        PROC(mvA, wA, dvA, scA);
        if (hasC) LOAD(e + 2 * nw, mvA, wA, dvA, scA);
        if (!hasB) break;
        bool hasD = (e + 3 * nw < N_EDGES);
        PROC(mvB, wB, dvB, scB);
        if (hasD) LOAD(e + 3 * nw, mvB, wB, dvB, scB);
        if (!hasC) break;
        e += 2 * nw;
        hasB = hasD;
    }
}

// msg_new = relu(agg + 2*(msg_old @ W_root + b_conv)); fp32 + fp16.
// 4 nodes/block; zeroes agg in-place for the next depth.
__global__ void k_combine(const float* __restrict__ msg_old, const float* __restrict__ Wr,
                          const float* __restrict__ bc,
                          float* __restrict__ agg,
                          float* __restrict__ msg_new, __half* __restrict__ msg16) {
    int tid = threadIdx.x;
    int n = blockIdx.x * 4 + (tid >> 6);
    int o = tid & 63;
    int q = tid >> 6;
    __shared__ float r[4][IN_DIM];
    r[q][o] = msg_old[(size_t)n * IN_DIM + o];
    __syncthreads();
    float root = bc[o];
    #pragma unroll
    for (int k = 0; k < IN_DIM; ++k) root = fmaf(r[q][k], Wr[k * IN_DIM + o], root);
    size_t idx = (size_t)n * IN_DIM + o;
    float a = agg[idx];
    agg[idx] = 0.f;
    float v = fmaxf(a + 2.f * root, 0.f);
    msg_new[idx] = v;
    msg16[idx] = __float2half(v);
}

// MFMA fused GEMM + relu + add-pool: out[g,:] += sum_n relu(msg16[n] @ WfpT^T + b_fp)
__global__ __launch_bounds__(256) void k_fp_pool_mfma(
    const __half* __restrict__ msg16, const __half* __restrict__ WfpT,
    const float* __restrict__ bfp, const int* __restrict__ gstart,
    float* __restrict__ out)
{
    const int tid = threadIdx.x, lane = tid & 63, wid = tid >> 6;
    const int g = blockIdx.y;
    const int cbase = blockIdx.x * 256 + wid * 64;
    const int l15 = lane & 15;
    const int kq = (lane >> 4) * 8;
    const int rq = (lane >> 4) * 4;

    const _Float16* wt = (const _Float16*)WfpT;
    const _Float16* mp = (const _Float16*)msg16;

    half8v bf[4][2];
    float bias[4];
    #pragma unroll
    for (int nf = 0; nf < 4; ++nf) {
        int n = cbase + nf * 16 + l15;
        #pragma unroll
        for (int kk = 0; kk < 2; ++kk)
            bf[nf][kk] = *(const half8v*)(wt + (size_t)n * IN_DIM + kk * 32 + kq);
        bias[nf] = bfp[n];
    }

    int n0g = gstart[g], n1g = gstart[g + 1];
    int len = n1g - n0g;
    int chunk = (len + (int)gridDim.z - 1) / (int)gridDim.z;
    int rs = n0g + (int)blockIdx.z * chunk;
    int re = min(rs + chunk, n1g);
    if (rs >= re) return;

    float pool[4] = {0.f, 0.f, 0.f, 0.f};
    int node0 = rs + l15; if (node0 >= n1g) node0 = n1g - 1;
    half8v af0 = *(const half8v*)(mp + (size_t)node0 * IN_DIM + kq);
    half8v af1 = *(const half8v*)(mp + (size_t)node0 * IN_DIM + 32 + kq);
    for (int r = rs; r < re; r += 16) {
        half8v nf0 = af0, nf1 = af1;
        if (r + 16 < re) {
            int node = r + 16 + l15; if (node >= n1g) node = n1g - 1;
            nf0 = *(const half8v*)(mp + (size_t)node * IN_DIM + kq);
            nf1 = *(const half8v*)(mp + (size_t)node * IN_DIM + 32 + kq);
        }
        #pragma unroll
        for (int nf = 0; nf < 4; ++nf) {
            float4v d = (float4v){0.f, 0.f, 0.f, 0.f};
            d = __builtin_amdgcn_mfma_f32_16x16x32_f16(af0, bf[nf][0], d, 0, 0, 0);
            d = __builtin_amdgcn_mfma_f32_16x16x32_f16(af1, bf[nf][1], d, 0, 0, 0);
            #pragma unroll
            for (int reg = 0; reg < 4; ++reg) {
                int rr = r + rq + reg;
                if (rr < re) pool[nf] += fmaxf(d[reg] + bias[nf], 0.f);
            }
        }
        af0 = nf0; af1 = nf1;
    }
    #pragma unroll
    for (int nf = 0; nf < 4; ++nf) {
        pool[nf] += __shfl_xor(pool[nf], 16);
        pool[nf] += __shfl_xor(pool[nf], 32);
    }
    if (lane < 16) {
        #pragma unroll
        for (int nf = 0; nf < 4; ++nf)
            atomicAdd(&out[(size_t)g * FP_DIM + cbase + nf * 16 + lane], pool[nf]);
    }
}

extern "C" void kernel_launch(void* const* d_in, const int* in_sizes, int n_in,
                              void* d_out, int out_size, void* d_ws, size_t ws_size,
                              hipStream_t stream) {
    const float* x        = (const float*)d_in[0];
    const int*   eidx     = (const int*)d_in[1];
    const float* ea       = (const float*)d_in[2];
    const int*   batch    = (const int*)d_in[3];
    const float* W_ae     = (const float*)d_in[4];
    const float* b_ae     = (const float*)d_in[5];
    const float* W_e1     = (const float*)d_in[6];
    const float* b_e1     = (const float*)d_in[7];
    const float* W_e2     = (const float*)d_in[8];
    const float* b_e2     = (const float*)d_in[9];
    const float* W_root   = (const float*)d_in[10];
    const float* b_conv   = (const float*)d_in[11];
    const float* W_fp     = (const float*)d_in[12];
    const float* b_fp     = (const float*)d_in[13];
    const int* src = eidx;
    const int* dst = eidx + N_EDGES;
    float* out = (float*)d_out;

    hipMemsetAsync(out, 0, (size_t)out_size * sizeof(float), stream);

    float* ws   = (float*)d_ws;
    float* msgA = ws;
    float* msgB = msgA + 640000;
    float* aggC = msgB + 640000;
    float* aggS = aggC + 640000;                        // unused (layout keep)
    float* cntC = aggS + 640000;
    float* cntS = cntC + 10000;
    int*   gst  = (int*)(cntS + 10000);                 // 32 ints

    __half* h16   = (__half*)(gst + 32);
    __half* W2T   = h16 + (size_t)N_EDGES * INTERNAL;
    __half* wbig  = W2T + (size_t)FP_DIM * INTERNAL;
    __half* msg16 = wbig + (size_t)N_EDGES * FP_DIM;
    __half* WfpT  = msg16 + (size_t)N_NODES * IN_DIM;

    size_t need = (4ull * 640000 + 2 * 10000 + 32) * 4
                + ((size_t)N_EDGES * INTERNAL + (size_t)FP_DIM * INTERNAL
                   + (size_t)N_EDGES * FP_DIM + (size_t)N_NODES * IN_DIM
                   + (size_t)FP_DIM * IN_DIM) * 2;
    if (ws_size < need) return;   // fail loudly (out stays 0)

    hipMemsetAsync(cntC, 0, 2 * (size_t)N_NODES * sizeof(float), stream);
    k_atom_expand<<<N_NODES / 4, 256, 0, stream>>>(x, W_ae, b_ae, msgA, msg16);
    k_edge_h16<<<N_EDGES / 2, 256, 0, stream>>>(ea, W_e1, b_e1, h16,
                                                dst, cntC, cntS, batch, gst, aggC);
    k_wt<<<128, 256, 0, stream>>>(W_e2, W_fp, W2T, WfpT);
    k_wgemm<<<dim3(FP_DIM / 128, (N_EDGES + 255) / 256), 512, 0, stream>>>(
        h16, W2T, b_e2, wbig);

    float* cur = msgA;
    float* nxt = msgB;
    for (int d = 0; d < DEPTH; ++d) {
        k_edge_apply<<<1024, 256, 0, stream>>>(
            cur, wbig, src, dst, ea, cntC, cntS, aggC);
        k_combine<<<N_NODES / 4, 256, 0, stream>>>(cur, W_root, b_conv, aggC,
                                                   nxt, msg16);
        k_fp_pool_mfma<<<dim3(FP_DIM / 256, N_GRAPHS, 4), 256, 0, stream>>>(
            msg16, WfpT, b_fp, gst, out);
        float* t = cur; cur = nxt; nxt = t;
    }
}